// Round 11
// baseline (163.374 us; speedup 1.0000x reference)
//
#include <hip/hip_runtime.h>
#include <hip/hip_bf16.h>

#define EMB 1024
#define NEXP 8
#define NH 1024
#define N_GU 2048
#define TOPK 2

#define BM 128
#define BN 128
#define BK 32
#define NSUB 32        // 1024 / 32
#define MAXTILES 72
#define GRID_GU (MAXTILES * 16)
#define CONV_BLKS 256

typedef __attribute__((ext_vector_type(4))) float f32x4;
typedef __attribute__((ext_vector_type(8))) short s16x8;
typedef __attribute__((ext_vector_type(4))) short s16x4;

typedef __attribute__((address_space(3))) unsigned int lds_u32;
typedef __attribute__((address_space(1))) const unsigned int glb_u32;

__device__ __forceinline__ void gl_lds16(const void* g, void* l) {
  __builtin_amdgcn_global_load_lds((glb_u32*)g, (lds_u32*)l, 16, 0, 0);
}

// raw barrier with compile-time memory fences
__device__ __forceinline__ void barrier_fence() {
  asm volatile("" ::: "memory");
  __builtin_amdgcn_s_barrier();
  asm volatile("" ::: "memory");
}

__device__ __forceinline__ unsigned short f2bf(float f) {
  union { float f; unsigned int u; } a; a.f = f;
  unsigned int u = a.u;
  unsigned int r = (u + 0x7FFFu + ((u >> 16) & 1u)) >> 16;
  return (unsigned short)r;
}

__device__ __forceinline__ float b2f(unsigned short h) {
  union { unsigned int u; float f; } a;
  a.u = ((unsigned int)h) << 16;
  return a.f;
}

// bijective chunked XCD swizzle (m204)
__device__ __forceinline__ int xcd_swz(int bid, int nwg) {
  int q = nwg >> 3, r = nwg & 7;
  int xcd = bid & 7, pos = bid >> 3;
  int base = (xcd < r) ? xcd * (q + 1) : r * (q + 1) + (xcd - r) * q;
  return base + pos;
}

// ---------------- fused router + fp32->bf16 conversion (x, gate_up_w only) ----------------
__global__ void convert_router(const float* __restrict__ x, unsigned short* __restrict__ xb, int n4x,
                               const float* __restrict__ guw, unsigned short* __restrict__ guwb, int n4g,
                               const float* __restrict__ rw, const float* __restrict__ rb, int T,
                               int* __restrict__ tokE, float* __restrict__ tokW) {
  int nr = T / 4;   // router blocks (4 waves = 4 tokens each)
  if ((int)blockIdx.x < nr) {
    int gwid = blockIdx.x * 4 + (threadIdx.x >> 6);
    int lane = threadIdx.x & 63;
    if (gwid >= T) return;
    const float* h = x + (size_t)gwid * EMB;
    float hreg[16];
    #pragma unroll
    for (int i = 0; i < 16; ++i) hreg[i] = h[lane + 64 * i];
    float sc[NEXP];
    #pragma unroll
    for (int e = 0; e < NEXP; ++e) {
      const float* w = rw + e * EMB;
      float s = 0.f;
      #pragma unroll
      for (int i = 0; i < 16; ++i) s += hreg[i] * w[lane + 64 * i];
      #pragma unroll
      for (int off = 32; off > 0; off >>= 1) s += __shfl_xor(s, off);
      sc[e] = s + rb[e];
    }
    if (lane == 0) {
      int e0 = 0; float v0 = sc[0];
      #pragma unroll
      for (int e = 1; e < NEXP; ++e) if (sc[e] > v0) { v0 = sc[e]; e0 = e; }
      int e1 = -1; float v1 = -3.0e38f;
      #pragma unroll
      for (int e = 0; e < NEXP; ++e) { if (e == e0) continue; if (sc[e] > v1) { v1 = sc[e]; e1 = e; } }
      float ex = __expf(v1 - v0);
      float w0 = 1.f / (1.f + ex);
      float w1 = ex / (1.f + ex);
      tokE[gwid * 2] = e0; tokE[gwid * 2 + 1] = e1;
      tokW[gwid * 2] = w0; tokW[gwid * 2 + 1] = w1;
    }
  } else {
    int tot = n4x + n4g;
    int base = (blockIdx.x - nr) * blockDim.x + threadIdx.x;
    int stride = (gridDim.x - nr) * blockDim.x;
    for (int i = base; i < tot; i += stride) {
      const float* src; unsigned short* dst; int k;
      if (i < n4x) { src = x; dst = xb; k = i; }
      else { src = guw; dst = guwb; k = i - n4x; }
      float4 v = ((const float4*)src)[k];
      s16x4 o;
      o[0] = (short)f2bf(v.x);
      o[1] = (short)f2bf(v.y);
      o[2] = (short)f2bf(v.z);
      o[3] = (short)f2bf(v.w);
      ((s16x4*)dst)[k] = o;
    }
  }
}

// ---------------- histogram + offsets + tile map ----------------
__global__ void count_meta(const int* __restrict__ tokE, int A,
                           int* __restrict__ offsets, int* __restrict__ tilemeta) {
  __shared__ int hist[NEXP];
  int t = threadIdx.x;
  if (t < NEXP) hist[t] = 0;
  __syncthreads();
  for (int i = t; i < A; i += blockDim.x) atomicAdd(&hist[tokE[i]], 1);
  __syncthreads();
  if (t == 0) {
    int off = 0, nt = 0;
    for (int e = 0; e < NEXP; ++e) {
      offsets[e] = off;
      int c = hist[e];
      int ntile = (c + BM - 1) / BM;
      for (int k = 0; k < ntile; ++k) {
        tilemeta[1 + nt * 3 + 0] = e;
        tilemeta[1 + nt * 3 + 1] = off + k * BM;
        tilemeta[1 + nt * 3 + 2] = off + c;
        nt++;
      }
      off += c;
    }
    offsets[NEXP] = off;
    tilemeta[0] = nt;
  }
}

// ---------------- scatter with wave-aggregated atomics ----------------
__global__ void scatter_tokens(const int* __restrict__ tokE, const int* __restrict__ offsets,
                               int* __restrict__ fill, int* __restrict__ rows,
                               int* __restrict__ apos, int A) {
  int i = blockIdx.x * blockDim.x + threadIdx.x;
  int lane = threadIdx.x & 63;
  int e = tokE[i];
  int p = -1;
  #pragma unroll
  for (int ex = 0; ex < NEXP; ++ex) {
    unsigned long long mask = __ballot(e == ex);
    if (mask) {
      int leader = __ffsll(mask) - 1;
      int cnt = __popcll(mask);
      int base = 0;
      if (lane == leader) base = atomicAdd(&fill[ex], cnt);
      base = __shfl(base, leader);
      if (e == ex) {
        int rank = __popcll(mask & ((1ull << lane) - 1ull));
        p = offsets[ex] + base + rank;
      }
    }
  }
  rows[p] = i >> 1;
  apos[i] = p;
}

// ---------------- grouped GEMM 1: BK=32 true-dbuf single-barrier pipeline + SwiGLU ----------------
// 2x16KB-per-operand buffers (32 KB total) keeps 4 blocks/CU; stage issued BEFORE compute
// so the end-of-iter vmcnt(0) drain is covered by the MFMA phase (T3 minimum recipe, m248).
// Extra CONV_BLKS blocks convert down_w fp32->bf16 (pure-BW work hidden under compute, m114).
__global__ __launch_bounds__(256, 4) void gemm_gate_up(
    const unsigned short* __restrict__ xb,
    const unsigned short* __restrict__ gub,
    const float* __restrict__ gu_bias,
    const int* __restrict__ rows,
    const int* __restrict__ tilemeta,
    unsigned short* __restrict__ hact,
    const float* __restrict__ dw, unsigned short* __restrict__ dwb, int n4d) {
  __shared__ __align__(16) short As[2][BM * BK];
  __shared__ __align__(16) short Bs[2][BN * BK];
  if ((int)blockIdx.x >= GRID_GU) {
    // converter role: down_w fp32 -> bf16
    int base = ((int)blockIdx.x - GRID_GU) * blockDim.x + threadIdx.x;
    int stride = CONV_BLKS * blockDim.x;
    for (int i = base; i < n4d; i += stride) {
      float4 v = ((const float4*)dw)[i];
      s16x4 o;
      o[0] = (short)f2bf(v.x);
      o[1] = (short)f2bf(v.y);
      o[2] = (short)f2bf(v.z);
      o[3] = (short)f2bf(v.w);
      ((s16x4*)dwb)[i] = o;
    }
    return;
  }
  int wg = xcd_swz(blockIdx.x, GRID_GU);
  int tileid = wg >> 4;          // n fast axis (N_GU/128 = 16)
  int n0 = (wg & 15) * BN;
  int nt = tilemeta[0];
  if (tileid >= nt) return;
  int e    = tilemeta[1 + tileid * 3 + 0];
  int m0   = tilemeta[1 + tileid * 3 + 1];
  int mEnd = tilemeta[1 + tileid * 3 + 2];

  int t = threadIdx.x;
  int lane = t & 63;
  int wid = t >> 6;
  int wr = wid >> 1, wc = wid & 1;

  // staging: instr q in {0,1} covers 16 rows at q*64 + wid*16; lane l -> row +(l>>2), chunk (l&3).
  // SOURCE pre-swizzle (rule #21, BK=32): global chunk (l&3) ^ ((l>>3)&3)  [s(row)=(row>>1)&3]
  int srow = lane >> 2;
  int scol = (((lane & 3) ^ ((lane >> 3) & 3)) * 8);
  const unsigned short* ga[2];
  const unsigned short* gb[2];
  int dstoff[2];
  #pragma unroll
  for (int q = 0; q < 2; ++q) {
    int rt = q * 64 + wid * 16 + srow;
    int ai = m0 + rt; if (ai >= mEnd) ai = mEnd - 1;
    ga[q] = xb + (size_t)rows[ai] * EMB + scol;
    gb[q] = gub + ((size_t)e * N_GU + n0 + rt) * EMB + scol;
    dstoff[q] = (q * 64 + wid * 16) * BK;
  }

  int fr = lane & 15;
  int kq = (lane >> 4) * 8;
  int rsw = ((fr & 7) >> 1) << 3;   // read-side swizzle: chunk ^= (row>>1)&3

  f32x4 acc[4][4];
  #pragma unroll
  for (int i = 0; i < 4; ++i)
    #pragma unroll
    for (int j = 0; j < 4; ++j) acc[i][j] = (f32x4){0.f, 0.f, 0.f, 0.f};

  // prologue: stage sub-tile 0 into buf 0, drain, rendezvous
  #pragma unroll
  for (int q = 0; q < 2; ++q) {
    gl_lds16(ga[q], &As[0][dstoff[q]]);
    gl_lds16(gb[q], &Bs[0][dstoff[q]]);
  }
  asm volatile("s_waitcnt vmcnt(0)" ::: "memory");
  barrier_fence();

  for (int tk = 0; tk < NSUB; ++tk) {
    int cur = tk & 1;
    if (tk + 1 < NSUB) {
      int k0 = (tk + 1) * BK;
      #pragma unroll
      for (int q = 0; q < 2; ++q) {
        gl_lds16(ga[q] + k0, &As[cur ^ 1][dstoff[q]]);
        gl_lds16(gb[q] + k0, &Bs[cur ^ 1][dstoff[q]]);
      }
    }
    s16x8 a[4], b[4];
    #pragma unroll
    for (int i = 0; i < 4; ++i)
      a[i] = *(const s16x8*)(&As[cur][(wr * 64 + i * 16 + fr) * BK + (kq ^ rsw)]);
    #pragma unroll
    for (int j = 0; j < 4; ++j)
      b[j] = *(const s16x8*)(&Bs[cur][(wc * 64 + j * 16 + fr) * BK + (kq ^ rsw)]);
    #pragma unroll
    for (int i = 0; i < 4; ++i)
      #pragma unroll
      for (int j = 0; j < 4; ++j)
        acc[i][j] = __builtin_amdgcn_mfma_f32_16x16x32_bf16(a[i], b[j], acc[i][j], 0, 0, 0);
    if (tk + 1 < NSUB) {
      asm volatile("s_waitcnt vmcnt(0)" ::: "memory");  // loads had the MFMA phase to land
      barrier_fence();
    }
  }

  // epilogue: bias + SwiGLU (pair even/odd N via shfl_xor 1) -> bf16 hact
  const float* bias_e = gu_bias + (size_t)e * N_GU;
  int rbase = m0 + wr * 64 + ((lane >> 4) * 4);
  #pragma unroll
  for (int i = 0; i < 4; ++i) {
    #pragma unroll
    for (int j = 0; j < 4; ++j) {
      int n = n0 + wc * 64 + j * 16 + fr;
      float v[4], o[4];
      #pragma unroll
      for (int r = 0; r < 4; ++r) v[r] = acc[i][j][r] + bias_e[n];
      #pragma unroll
      for (int r = 0; r < 4; ++r) o[r] = __shfl_xor(v[r], 1);
      if ((lane & 1) == 0) {
        int outc = n >> 1;
        #pragma unroll
        for (int r = 0; r < 4; ++r) {
          int pos = rbase + i * 16 + r;
          if (pos < mEnd) {
            float g = v[r], u = o[r];
            float gc = fminf(fmaxf(g, -7.f), 7.f);
            float uc = fminf(fmaxf(u, -7.f), 7.f);
            float sig = 1.f / (1.f + __expf(-1.702f * g));
            float act = gc * sig * (uc + 1.f);
            hact[(size_t)pos * NH + outc] = f2bf(act);
          }
        }
      }
    }
  }
}

// ---------------- grouped GEMM 2: same BK=32 pipeline, hact @ down_w^T -> y (bf16) ----------------
__global__ __launch_bounds__(256, 4) void gemm_down(
    const unsigned short* __restrict__ hact,
    const unsigned short* __restrict__ dwb,
    const int* __restrict__ tilemeta,
    unsigned short* __restrict__ y) {
  __shared__ __align__(16) short As[2][BM * BK];
  __shared__ __align__(16) short Bs[2][BN * BK];
  int wg = xcd_swz(blockIdx.x, gridDim.x);
  int tileid = wg >> 3;          // n fast axis (EMB/128 = 8)
  int n0 = (wg & 7) * BN;
  int nt = tilemeta[0];
  if (tileid >= nt) return;
  int e    = tilemeta[1 + tileid * 3 + 0];
  int m0   = tilemeta[1 + tileid * 3 + 1];
  int mEnd = tilemeta[1 + tileid * 3 + 2];

  int t = threadIdx.x;
  int lane = t & 63;
  int wid = t >> 6;
  int wr = wid >> 1, wc = wid & 1;

  int srow = lane >> 2;
  int scol = (((lane & 3) ^ ((lane >> 3) & 3)) * 8);
  const unsigned short* ga[2];
  const unsigned short* gb[2];
  int dstoff[2];
  #pragma unroll
  for (int q = 0; q < 2; ++q) {
    int rt = q * 64 + wid * 16 + srow;
    int ai = m0 + rt; if (ai >= mEnd) ai = mEnd - 1;
    ga[q] = hact + (size_t)ai * NH + scol;
    gb[q] = dwb + ((size_t)e * EMB + n0 + rt) * NH + scol;
    dstoff[q] = (q * 64 + wid * 16) * BK;
  }

  int fr = lane & 15;
  int kq = (lane >> 4) * 8;
  int rsw = ((fr & 7) >> 1) << 3;

  f32x4 acc[4][4];
  #pragma unroll
  for (int i = 0; i < 4; ++i)
    #pragma unroll
    for (int j = 0; j < 4; ++j) acc[i][j] = (f32x4){0.f, 0.f, 0.f, 0.f};

  #pragma unroll
  for (int q = 0; q < 2; ++q) {
    gl_lds16(ga[q], &As[0][dstoff[q]]);
    gl_lds16(gb[q], &Bs[0][dstoff[q]]);
  }
  asm volatile("s_waitcnt vmcnt(0)" ::: "memory");
  barrier_fence();

  for (int tk = 0; tk < NSUB; ++tk) {
    int cur = tk & 1;
    if (tk + 1 < NSUB) {
      int k0 = (tk + 1) * BK;
      #pragma unroll
      for (int q = 0; q < 2; ++q) {
        gl_lds16(ga[q] + k0, &As[cur ^ 1][dstoff[q]]);
        gl_lds16(gb[q] + k0, &Bs[cur ^ 1][dstoff[q]]);
      }
    }
    s16x8 a[4], b[4];
    #pragma unroll
    for (int i = 0; i < 4; ++i)
      a[i] = *(const s16x8*)(&As[cur][(wr * 64 + i * 16 + fr) * BK + (kq ^ rsw)]);
    #pragma unroll
    for (int j = 0; j < 4; ++j)
      b[j] = *(const s16x8*)(&Bs[cur][(wc * 64 + j * 16 + fr) * BK + (kq ^ rsw)]);
    #pragma unroll
    for (int i = 0; i < 4; ++i)
      #pragma unroll
      for (int j = 0; j < 4; ++j)
        acc[i][j] = __builtin_amdgcn_mfma_f32_16x16x32_bf16(a[i], b[j], acc[i][j], 0, 0, 0);
    if (tk + 1 < NSUB) {
      asm volatile("s_waitcnt vmcnt(0)" ::: "memory");
      barrier_fence();
    }
  }

  int rbase = m0 + wr * 64 + ((lane >> 4) * 4);
  #pragma unroll
  for (int i = 0; i < 4; ++i) {
    #pragma unroll
    for (int j = 0; j < 4; ++j) {
      int n = n0 + wc * 64 + j * 16 + fr;
      #pragma unroll
      for (int r = 0; r < 4; ++r) {
        int pos = rbase + i * 16 + r;
        if (pos < mEnd) y[(size_t)pos * EMB + n] = f2bf(acc[i][j][r]);
      }
    }
  }
}

// ---------------- final combine (bf16 y) ----------------
__global__ void combine_out(const unsigned short* __restrict__ y, const float* __restrict__ down_b,
                            const int* __restrict__ tokE, const float* __restrict__ tokW,
                            const int* __restrict__ apos, float* __restrict__ out, int T) {
  int i = blockIdx.x * blockDim.x + threadIdx.x;
  int tot = T * (EMB / 4);
  if (i >= tot) return;
  int tok = i >> 8;
  int c = i & 255;
  int e0 = tokE[tok * 2], e1 = tokE[tok * 2 + 1];
  float w0 = tokW[tok * 2], w1 = tokW[tok * 2 + 1];
  int p0 = apos[tok * 2], p1 = apos[tok * 2 + 1];
  s16x4 v0 = ((const s16x4*)(y + (size_t)p0 * EMB))[c];
  s16x4 v1 = ((const s16x4*)(y + (size_t)p1 * EMB))[c];
  float4 b0 = ((const float4*)(down_b + (size_t)e0 * EMB))[c];
  float4 b1 = ((const float4*)(down_b + (size_t)e1 * EMB))[c];
  float4 o;
  o.x = w0 * (b2f((unsigned short)v0[0]) + b0.x) + w1 * (b2f((unsigned short)v1[0]) + b1.x);
  o.y = w0 * (b2f((unsigned short)v0[1]) + b0.y) + w1 * (b2f((unsigned short)v1[1]) + b1.y);
  o.z = w0 * (b2f((unsigned short)v0[2]) + b0.z) + w1 * (b2f((unsigned short)v1[2]) + b1.z);
  o.w = w0 * (b2f((unsigned short)v0[3]) + b0.w) + w1 * (b2f((unsigned short)v1[3]) + b1.w);
  ((float4*)out)[i] = o;
}

extern "C" void kernel_launch(void* const* d_in, const int* in_sizes, int n_in,
                              void* d_out, int out_size, void* d_ws, size_t ws_size,
                              hipStream_t stream) {
  const float* x   = (const float*)d_in[0];
  const float* rw  = (const float*)d_in[1];
  const float* rb  = (const float*)d_in[2];
  const float* guw = (const float*)d_in[3];
  const float* gub = (const float*)d_in[4];
  const float* dw  = (const float*)d_in[5];
  const float* db  = (const float*)d_in[6];
  float* out = (float*)d_out;

  int T = in_sizes[0] / EMB;   // 4096
  int A = T * TOPK;            // 8192

  char* ws = (char*)d_ws;
  size_t off = 0;
  auto alloc = [&](size_t bytes) -> void* {
    void* p = ws + off;
    off = (off + bytes + 255) & ~((size_t)255);
    return p;
  };
  unsigned short* xb   = (unsigned short*)alloc((size_t)T * EMB * 2);
  unsigned short* guwb = (unsigned short*)alloc((size_t)NEXP * N_GU * EMB * 2);
  unsigned short* dwb  = (unsigned short*)alloc((size_t)NEXP * EMB * NH * 2);
  unsigned short* hact = (unsigned short*)alloc((size_t)A * NH * 2);
  unsigned short* y    = (unsigned short*)alloc((size_t)A * EMB * 2);
  int*   tokE    = (int*)alloc((size_t)A * 4);
  float* tokW    = (float*)alloc((size_t)A * 4);
  int*   apos    = (int*)alloc((size_t)A * 4);
  int*   rowsArr = (int*)alloc((size_t)A * 4);
  int*   fill    = (int*)alloc(NEXP * 4);
  int*   offsets = (int*)alloc((NEXP + 1) * 4);
  int*   tilemeta= (int*)alloc((1 + MAXTILES * 3) * 4);

  hipMemsetAsync(fill, 0, NEXP * 4, stream);

  int n4x = T * EMB / 4;
  int n4g = NEXP * N_GU * EMB / 4;
  int n4d = NEXP * EMB * NH / 4;
  convert_router<<<T / 4 + 2048, 256, 0, stream>>>(x, xb, n4x, guw, guwb, n4g,
                                                   rw, rb, T, tokE, tokW);

  count_meta<<<1, 1024, 0, stream>>>(tokE, A, offsets, tilemeta);
  scatter_tokens<<<A / 256, 256, 0, stream>>>(tokE, offsets, fill, rowsArr, apos, A);

  gemm_gate_up<<<GRID_GU + CONV_BLKS, 256, 0, stream>>>(xb, guwb, gub, rowsArr, tilemeta, hact,
                                                        dw, dwb, n4d);
  gemm_down<<<MAXTILES * (EMB / BN), 256, 0, stream>>>(hact, dwb, tilemeta, y);

  combine_out<<<(T * EMB / 4 + 255) / 256, 256, 0, stream>>>(y, db, tokE, tokW, apos, out, T);
}

// Round 12
// 140.040 us; speedup vs baseline: 1.1666x; 1.1666x over previous
//
#include <hip/hip_runtime.h>
#include <hip/hip_bf16.h>

#define EMB 1024
#define NEXP 8
#define NH 1024
#define N_GU 2048
#define TOPK 2

#define BM 128
#define BN 128
#define BK 64
#define KTILES 16      // 1024 / 64
#define MAXTILES 72

typedef __attribute__((ext_vector_type(4))) float f32x4;
typedef __attribute__((ext_vector_type(8))) short s16x8;
typedef __attribute__((ext_vector_type(4))) short s16x4;

typedef __attribute__((address_space(3))) unsigned int lds_u32;
typedef __attribute__((address_space(1))) const unsigned int glb_u32;

__device__ __forceinline__ void gl_lds16(const void* g, void* l) {
  __builtin_amdgcn_global_load_lds((glb_u32*)g, (lds_u32*)l, 16, 0, 0);
}

__device__ __forceinline__ unsigned short f2bf(float f) {
  union { float f; unsigned int u; } a; a.f = f;
  unsigned int u = a.u;
  unsigned int r = (u + 0x7FFFu + ((u >> 16) & 1u)) >> 16;
  return (unsigned short)r;
}

__device__ __forceinline__ float b2f(unsigned short h) {
  union { unsigned int u; float f; } a;
  a.u = ((unsigned int)h) << 16;
  return a.f;
}

// bijective chunked XCD swizzle (m204)
__device__ __forceinline__ int xcd_swz(int bid, int nwg) {
  int q = nwg >> 3, r = nwg & 7;
  int xcd = bid & 7, pos = bid >> 3;
  int base = (xcd < r) ? xcd * (q + 1) : r * (q + 1) + (xcd - r) * q;
  return base + pos;
}

// ---------------- fused router + fp32->bf16 conversion (block-role partition) ----------------
__global__ void convert_router(const float* __restrict__ x, unsigned short* __restrict__ xb, int n4x,
                               const float* __restrict__ guw, unsigned short* __restrict__ guwb, int n4g,
                               const float* __restrict__ dw, unsigned short* __restrict__ dwb, int n4d,
                               const float* __restrict__ rw, const float* __restrict__ rb, int T,
                               int* __restrict__ tokE, float* __restrict__ tokW) {
  int nr = T / 4;   // router blocks (4 waves = 4 tokens each)
  if ((int)blockIdx.x < nr) {
    int gwid = blockIdx.x * 4 + (threadIdx.x >> 6);
    int lane = threadIdx.x & 63;
    if (gwid >= T) return;
    const float* h = x + (size_t)gwid * EMB;
    float hreg[16];
    #pragma unroll
    for (int i = 0; i < 16; ++i) hreg[i] = h[lane + 64 * i];
    float sc[NEXP];
    #pragma unroll
    for (int e = 0; e < NEXP; ++e) {
      const float* w = rw + e * EMB;
      float s = 0.f;
      #pragma unroll
      for (int i = 0; i < 16; ++i) s += hreg[i] * w[lane + 64 * i];
      #pragma unroll
      for (int off = 32; off > 0; off >>= 1) s += __shfl_xor(s, off);
      sc[e] = s + rb[e];
    }
    if (lane == 0) {
      int e0 = 0; float v0 = sc[0];
      #pragma unroll
      for (int e = 1; e < NEXP; ++e) if (sc[e] > v0) { v0 = sc[e]; e0 = e; }
      int e1 = -1; float v1 = -3.0e38f;
      #pragma unroll
      for (int e = 0; e < NEXP; ++e) { if (e == e0) continue; if (sc[e] > v1) { v1 = sc[e]; e1 = e; } }
      float ex = __expf(v1 - v0);
      float w0 = 1.f / (1.f + ex);
      float w1 = ex / (1.f + ex);
      tokE[gwid * 2] = e0; tokE[gwid * 2 + 1] = e1;
      tokW[gwid * 2] = w0; tokW[gwid * 2 + 1] = w1;
    }
  } else {
    int tot = n4x + n4g + n4d;
    int base = (blockIdx.x - nr) * blockDim.x + threadIdx.x;
    int stride = (gridDim.x - nr) * blockDim.x;
    for (int i = base; i < tot; i += stride) {
      const float* src; unsigned short* dst; int k;
      if (i < n4x) { src = x; dst = xb; k = i; }
      else if (i < n4x + n4g) { src = guw; dst = guwb; k = i - n4x; }
      else { src = dw; dst = dwb; k = i - n4x - n4g; }
      float4 v = ((const float4*)src)[k];
      s16x4 o;
      o[0] = (short)f2bf(v.x);
      o[1] = (short)f2bf(v.y);
      o[2] = (short)f2bf(v.z);
      o[3] = (short)f2bf(v.w);
      ((s16x4*)dst)[k] = o;
    }
  }
}

// ---------------- fused histogram + offsets + tile map + scatter (single block) ----------------
__global__ void meta_scatter(const int* __restrict__ tokE, int A,
                             int* __restrict__ tilemeta,
                             int* __restrict__ rows, int* __restrict__ apos) {
  __shared__ int hist[NEXP];
  __shared__ int offs[NEXP];
  __shared__ int fill[NEXP];
  int t = threadIdx.x;
  if (t < NEXP) { hist[t] = 0; fill[t] = 0; }
  __syncthreads();
  for (int i = t; i < A; i += blockDim.x) atomicAdd(&hist[tokE[i]], 1);
  __syncthreads();
  if (t == 0) {
    int off = 0, nt = 0;
    for (int e = 0; e < NEXP; ++e) {
      offs[e] = off;
      int c = hist[e];
      int ntile = (c + BM - 1) / BM;
      for (int k = 0; k < ntile; ++k) {
        tilemeta[1 + nt * 3 + 0] = e;
        tilemeta[1 + nt * 3 + 1] = off + k * BM;
        tilemeta[1 + nt * 3 + 2] = off + c;
        nt++;
      }
      off += c;
    }
    tilemeta[0] = nt;
  }
  __syncthreads();
  for (int i = t; i < A; i += blockDim.x) {
    int e = tokE[i];
    int p = offs[e] + atomicAdd(&fill[e], 1);
    rows[p] = i >> 1;
    apos[i] = p;
  }
}

// ---------------- grouped GEMM 1: gathered x @ gate_up_w[e]^T, fused SwiGLU ----------------
// single-buffer 32KB LDS; cross-block overlap hides stage drain (m97/m114).
// Structural note (R3-R11 ledger): dbuf/counted-vmcnt/256^2/BK32 variants ALL regress vs
// this plain 2-barrier loop at 4 blocks/CU — do not re-trade occupancy for pipelining.
__global__ __launch_bounds__(256, 4) void gemm_gate_up(
    const unsigned short* __restrict__ xb,
    const unsigned short* __restrict__ gub,
    const float* __restrict__ gu_bias,
    const int* __restrict__ rows,
    const int* __restrict__ tilemeta,
    unsigned short* __restrict__ hact) {
  __shared__ __align__(16) short As[BM * BK];
  __shared__ __align__(16) short Bs[BN * BK];
  int wg = xcd_swz(blockIdx.x, gridDim.x);
  int tileid = wg >> 4;          // n = wg & 15 fast axis (A-tile reuse adjacency)
  int n0 = (wg & 15) * BN;
  int nt = tilemeta[0];
  if (tileid >= nt) return;
  int e    = tilemeta[1 + tileid * 3 + 0];
  int m0   = tilemeta[1 + tileid * 3 + 1];
  int mEnd = tilemeta[1 + tileid * 3 + 2];

  int t = threadIdx.x;
  int lane = t & 63;
  int wid = t >> 6;
  int wr = wid >> 1, wc = wid & 1;

  // staging: inst q covers rows wid*32+q*8..+8; lane l -> row +(l>>3), LDS chunk (l&7).
  // SOURCE pre-swizzle (rule #21): fetch global chunk (l&7) ^ (row&7).
  int srow = lane >> 3;
  int scol = (((lane & 7) ^ (srow & 7)) * 8);
  const unsigned short* ga[4];
  const unsigned short* gb[4];
  int dstoff[4];
  #pragma unroll
  for (int q = 0; q < 4; ++q) {
    int rt = wid * 32 + q * 8 + srow;
    int ai = m0 + rt; if (ai >= mEnd) ai = mEnd - 1;
    ga[q] = xb + (size_t)rows[ai] * EMB + scol;
    gb[q] = gub + ((size_t)e * N_GU + n0 + rt) * EMB + scol;
    dstoff[q] = (wid * 32 + q * 8) * BK;
  }

  int fr = lane & 15;
  int q8 = (lane >> 4) * 8;
  int rsw = (fr & 7) << 3;       // read-side swizzle (elem), row&7 = fr&7

  f32x4 acc[4][4];
  #pragma unroll
  for (int i = 0; i < 4; ++i)
    #pragma unroll
    for (int j = 0; j < 4; ++j) acc[i][j] = (f32x4){0.f, 0.f, 0.f, 0.f};

  for (int tk = 0; tk < KTILES; ++tk) {
    int k0 = tk * BK;
    __syncthreads();             // buffer free (previous compute done)
    #pragma unroll
    for (int q = 0; q < 4; ++q) {
      gl_lds16(ga[q] + k0, &As[dstoff[q]]);
      gl_lds16(gb[q] + k0, &Bs[dstoff[q]]);
    }
    __syncthreads();             // implicit vmcnt(0) drain: tile visible to all waves
    #pragma unroll
    for (int kk = 0; kk < BK; kk += 32) {
      s16x8 a[4], b[4];
      #pragma unroll
      for (int i = 0; i < 4; ++i)
        a[i] = *(const s16x8*)(&As[(wr * 64 + i * 16 + fr) * BK + ((kk + q8) ^ rsw)]);
      #pragma unroll
      for (int j = 0; j < 4; ++j)
        b[j] = *(const s16x8*)(&Bs[(wc * 64 + j * 16 + fr) * BK + ((kk + q8) ^ rsw)]);
      #pragma unroll
      for (int i = 0; i < 4; ++i)
        #pragma unroll
        for (int j = 0; j < 4; ++j)
          acc[i][j] = __builtin_amdgcn_mfma_f32_16x16x32_bf16(a[i], b[j], acc[i][j], 0, 0, 0);
    }
  }

  // epilogue: bias + SwiGLU (pair even/odd N via shfl_xor 1) -> bf16 hact
  const float* bias_e = gu_bias + (size_t)e * N_GU;
  int rbase = m0 + wr * 64 + ((lane >> 4) * 4);
  #pragma unroll
  for (int i = 0; i < 4; ++i) {
    #pragma unroll
    for (int j = 0; j < 4; ++j) {
      int n = n0 + wc * 64 + j * 16 + fr;
      float v[4], o[4];
      #pragma unroll
      for (int r = 0; r < 4; ++r) v[r] = acc[i][j][r] + bias_e[n];
      #pragma unroll
      for (int r = 0; r < 4; ++r) o[r] = __shfl_xor(v[r], 1);
      if ((lane & 1) == 0) {
        int outc = n >> 1;
        #pragma unroll
        for (int r = 0; r < 4; ++r) {
          int pos = rbase + i * 16 + r;
          if (pos < mEnd) {
            float g = v[r], u = o[r];
            float gc = fminf(fmaxf(g, -7.f), 7.f);
            float uc = fminf(fmaxf(u, -7.f), 7.f);
            float sig = 1.f / (1.f + __expf(-1.702f * g));
            float act = gc * sig * (uc + 1.f);
            hact[(size_t)pos * NH + outc] = f2bf(act);
          }
        }
      }
    }
  }
}

// ---------------- grouped GEMM 2: hact @ down_w[e]^T -> y (bf16) ----------------
__global__ __launch_bounds__(256, 4) void gemm_down(
    const unsigned short* __restrict__ hact,
    const unsigned short* __restrict__ dwb,
    const int* __restrict__ tilemeta,
    unsigned short* __restrict__ y) {
  __shared__ __align__(16) short As[BM * BK];
  __shared__ __align__(16) short Bs[BN * BK];
  int wg = xcd_swz(blockIdx.x, gridDim.x);
  int tileid = wg >> 3;          // n = wg & 7 fast axis
  int n0 = (wg & 7) * BN;
  int nt = tilemeta[0];
  if (tileid >= nt) return;
  int e    = tilemeta[1 + tileid * 3 + 0];
  int m0   = tilemeta[1 + tileid * 3 + 1];
  int mEnd = tilemeta[1 + tileid * 3 + 2];

  int t = threadIdx.x;
  int lane = t & 63;
  int wid = t >> 6;
  int wr = wid >> 1, wc = wid & 1;

  int srow = lane >> 3;
  int scol = (((lane & 7) ^ (srow & 7)) * 8);
  const unsigned short* ga[4];
  const unsigned short* gb[4];
  int dstoff[4];
  #pragma unroll
  for (int q = 0; q < 4; ++q) {
    int rt = wid * 32 + q * 8 + srow;
    int ai = m0 + rt; if (ai >= mEnd) ai = mEnd - 1;
    ga[q] = hact + (size_t)ai * NH + scol;
    gb[q] = dwb + ((size_t)e * EMB + n0 + rt) * NH + scol;
    dstoff[q] = (wid * 32 + q * 8) * BK;
  }

  int fr = lane & 15;
  int q8 = (lane >> 4) * 8;
  int rsw = (fr & 7) << 3;

  f32x4 acc[4][4];
  #pragma unroll
  for (int i = 0; i < 4; ++i)
    #pragma unroll
    for (int j = 0; j < 4; ++j) acc[i][j] = (f32x4){0.f, 0.f, 0.f, 0.f};

  for (int tk = 0; tk < KTILES; ++tk) {
    int k0 = tk * BK;
    __syncthreads();
    #pragma unroll
    for (int q = 0; q < 4; ++q) {
      gl_lds16(ga[q] + k0, &As[dstoff[q]]);
      gl_lds16(gb[q] + k0, &Bs[dstoff[q]]);
    }
    __syncthreads();
    #pragma unroll
    for (int kk = 0; kk < BK; kk += 32) {
      s16x8 a[4], b[4];
      #pragma unroll
      for (int i = 0; i < 4; ++i)
        a[i] = *(const s16x8*)(&As[(wr * 64 + i * 16 + fr) * BK + ((kk + q8) ^ rsw)]);
      #pragma unroll
      for (int j = 0; j < 4; ++j)
        b[j] = *(const s16x8*)(&Bs[(wc * 64 + j * 16 + fr) * BK + ((kk + q8) ^ rsw)]);
      #pragma unroll
      for (int i = 0; i < 4; ++i)
        #pragma unroll
        for (int j = 0; j < 4; ++j)
          acc[i][j] = __builtin_amdgcn_mfma_f32_16x16x32_bf16(a[i], b[j], acc[i][j], 0, 0, 0);
    }
  }

  int rbase = m0 + wr * 64 + ((lane >> 4) * 4);
  #pragma unroll
  for (int i = 0; i < 4; ++i) {
    #pragma unroll
    for (int j = 0; j < 4; ++j) {
      int n = n0 + wc * 64 + j * 16 + fr;
      #pragma unroll
      for (int r = 0; r < 4; ++r) {
        int pos = rbase + i * 16 + r;
        if (pos < mEnd) y[(size_t)pos * EMB + n] = f2bf(acc[i][j][r]);
      }
    }
  }
}

// ---------------- final combine (bf16 y) ----------------
__global__ void combine_out(const unsigned short* __restrict__ y, const float* __restrict__ down_b,
                            const int* __restrict__ tokE, const float* __restrict__ tokW,
                            const int* __restrict__ apos, float* __restrict__ out, int T) {
  int i = blockIdx.x * blockDim.x + threadIdx.x;
  int tot = T * (EMB / 4);
  if (i >= tot) return;
  int tok = i >> 8;
  int c = i & 255;
  int e0 = tokE[tok * 2], e1 = tokE[tok * 2 + 1];
  float w0 = tokW[tok * 2], w1 = tokW[tok * 2 + 1];
  int p0 = apos[tok * 2], p1 = apos[tok * 2 + 1];
  s16x4 v0 = ((const s16x4*)(y + (size_t)p0 * EMB))[c];
  s16x4 v1 = ((const s16x4*)(y + (size_t)p1 * EMB))[c];
  float4 b0 = ((const float4*)(down_b + (size_t)e0 * EMB))[c];
  float4 b1 = ((const float4*)(down_b + (size_t)e1 * EMB))[c];
  float4 o;
  o.x = w0 * (b2f((unsigned short)v0[0]) + b0.x) + w1 * (b2f((unsigned short)v1[0]) + b1.x);
  o.y = w0 * (b2f((unsigned short)v0[1]) + b0.y) + w1 * (b2f((unsigned short)v1[1]) + b1.y);
  o.z = w0 * (b2f((unsigned short)v0[2]) + b0.z) + w1 * (b2f((unsigned short)v1[2]) + b1.z);
  o.w = w0 * (b2f((unsigned short)v0[3]) + b0.w) + w1 * (b2f((unsigned short)v1[3]) + b1.w);
  ((float4*)out)[i] = o;
}

extern "C" void kernel_launch(void* const* d_in, const int* in_sizes, int n_in,
                              void* d_out, int out_size, void* d_ws, size_t ws_size,
                              hipStream_t stream) {
  const float* x   = (const float*)d_in[0];
  const float* rw  = (const float*)d_in[1];
  const float* rb  = (const float*)d_in[2];
  const float* guw = (const float*)d_in[3];
  const float* gub = (const float*)d_in[4];
  const float* dw  = (const float*)d_in[5];
  const float* db  = (const float*)d_in[6];
  float* out = (float*)d_out;

  int T = in_sizes[0] / EMB;   // 4096
  int A = T * TOPK;            // 8192

  char* ws = (char*)d_ws;
  size_t off = 0;
  auto alloc = [&](size_t bytes) -> void* {
    void* p = ws + off;
    off = (off + bytes + 255) & ~((size_t)255);
    return p;
  };
  unsigned short* xb   = (unsigned short*)alloc((size_t)T * EMB * 2);
  unsigned short* guwb = (unsigned short*)alloc((size_t)NEXP * N_GU * EMB * 2);
  unsigned short* dwb  = (unsigned short*)alloc((size_t)NEXP * EMB * NH * 2);
  unsigned short* hact = (unsigned short*)alloc((size_t)A * NH * 2);
  unsigned short* y    = (unsigned short*)alloc((size_t)A * EMB * 2);
  int*   tokE    = (int*)alloc((size_t)A * 4);
  float* tokW    = (float*)alloc((size_t)A * 4);
  int*   apos    = (int*)alloc((size_t)A * 4);
  int*   rowsArr = (int*)alloc((size_t)A * 4);
  int*   tilemeta= (int*)alloc((1 + MAXTILES * 3) * 4);

  int n4x = T * EMB / 4;
  int n4g = NEXP * N_GU * EMB / 4;
  int n4d = NEXP * EMB * NH / 4;
  convert_router<<<T / 4 + 2048, 256, 0, stream>>>(x, xb, n4x, guw, guwb, n4g, dw, dwb, n4d,
                                                   rw, rb, T, tokE, tokW);

  meta_scatter<<<1, 1024, 0, stream>>>(tokE, A, tilemeta, rowsArr, apos);

  gemm_gate_up<<<MAXTILES * (N_GU / BN), 256, 0, stream>>>(xb, guwb, gub, rowsArr, tilemeta, hact);
  gemm_down<<<MAXTILES * (EMB / BN), 256, 0, stream>>>(hact, dwb, tilemeta, y);

  combine_out<<<(T * EMB / 4 + 255) / 256, 256, 0, stream>>>(y, db, tokE, tokW, apos, out, T);
}